// Round 13
// baseline (189.295 us; speedup 1.0000x reference)
//
#include <hip/hip_runtime.h>
#include <cstdint>
#include <cstddef>

#define NEGV (-1e30f)
#define IL2f 1.44269504088896340736f
#define LN2f 0.693147180559945309417f

__device__ __forceinline__ float exp2_hw(float x) { return __builtin_amdgcn_exp2f(x); }
__device__ __forceinline__ float log2_hw(float x) { return __builtin_amdgcn_logf(x); }

constexpr int Nn = 64, Cc = 64, Tt = 4000, Ss = 100;

__device__ __forceinline__ float wave_shr1(float x) {  // lane n <- lane n-1
    return __int_as_float(__builtin_amdgcn_update_dpp(0, __float_as_int(x), 0x138, 0xF, 0xF, true));
}
__device__ __forceinline__ float wave_shl1(float x) {  // lane n <- lane n+1
    return __int_as_float(__builtin_amdgcn_update_dpp(0, __float_as_int(x), 0x130, 0xF, 0xF, true));
}
__device__ __forceinline__ int wave_shr1_i(int x) {
    return __builtin_amdgcn_update_dpp(0, x, 0x138, 0xF, 0xF, true);
}
__device__ __forceinline__ int wave_shl1_i(int x) {
    return __builtin_amdgcn_update_dpp(0, x, 0x130, 0xF, 0xF, true);
}

typedef float f4 __attribute__((ext_vector_type(4)));
typedef float f2 __attribute__((ext_vector_type(2)));
#define LD4(p) (*(const f4*)(p))

__device__ __forceinline__ void gload16(const float* g, float* l) {
    __builtin_amdgcn_global_load_lds(
        (const __attribute__((address_space(1))) void*)g,
        (__attribute__((address_space(3))) void*)l, 16, 0, 0);
}

// ---------------- Kernel 1a: per-(n,t) log2-softmax denominator ----------------
__global__ __launch_bounds__(256) void ctc_denom_kernel(
    const float* __restrict__ logits, float* __restrict__ d2)
{
    const int t4 = (blockIdx.x * 256 + threadIdx.x) * 4;
    const int n = blockIdx.y;
    if (t4 >= Tt) return;
    const float* __restrict__ p = logits + (size_t)n * Cc * Tt + t4;
    f4 m, s;
    {
        f4 v = LD4(p);
        #pragma unroll
        for (int i = 0; i < 4; ++i) { m[i] = v[i] * IL2f; s[i] = 1.f; }
    }
    #pragma unroll 4
    for (int c = 1; c < Cc; ++c) {
        f4 v = LD4(p + (size_t)c * Tt);
        #pragma unroll
        for (int i = 0; i < 4; ++i) {
            float vi = v[i] * IL2f;
            float nm = fmaxf(m[i], vi);
            s[i] = s[i] * exp2_hw(m[i] - nm) + exp2_hw(vi - nm);
            m[i] = nm;
        }
    }
    f4 o;
    #pragma unroll
    for (int i = 0; i < 4; ++i) o[i] = m[i] + log2_hw(s[i]);
    *(f4*)(d2 + (size_t)n * Tt + t4) = o;
}

// ---------------- Kernel 1b: softmax probabilities ----------------
__global__ __launch_bounds__(256) void ctc_prob_kernel(
    const float* __restrict__ logits, const float* __restrict__ d2, float* __restrict__ P)
{
    const int t4 = (blockIdx.x * 256 + threadIdx.x) * 4;
    const int n = blockIdx.y;
    const int c0 = blockIdx.z * 8;
    if (t4 >= Tt) return;
    const f4 d = LD4(d2 + (size_t)n * Tt + t4);
    const float* __restrict__ src = logits + ((size_t)n * Cc + c0) * Tt + t4;
    float* __restrict__ dst = P + ((size_t)n * Cc + c0) * Tt + t4;
    #pragma unroll
    for (int c = 0; c < 8; ++c) {
        f4 v = LD4(src + (size_t)c * Tt);
        f4 o;
        #pragma unroll
        for (int i = 0; i < 4; ++i) o[i] = exp2_hw(fmaf(v[i], IL2f, -d[i]));
        *(f4*)(dst + (size_t)c * Tt) = o;
    }
}

// ---------------- Kernel 2: fwd AND bwd chains fused in ONE wave ----------------
// R12 showed fb is DEPENDENCY-STALL-bound (~5cy/instr, in-order single wave).
// Fix: one block per sample; the wave holds both chains' states and the body
// interleaves F/B step pairs — each chain's producer latency is hidden by the
// other chain's instructions. 32-step groups, per-direction 2-slot LDS ring,
// staggered counted vmcnt(24) (outstanding <= 48 < 63 counter max).
template<bool PRE>
__global__ __launch_bounds__(64) void ctc_fb_kernel(
    const float* __restrict__ PR, const int* __restrict__ targets,
    const int* __restrict__ tlen, const int* __restrict__ ilen,
    const float* __restrict__ d2, float* __restrict__ wsA, float* __restrict__ wsB)
{
    constexpr int NA = PRE ? 3 : 4;
    __shared__ float lds[2][2][NA][8][64][4];   // dir, slot, arr, sub, lane, 4

    const int n = blockIdx.x;
    const int lane = threadIdx.x;
    const int tl = tlen[n];
    const int Tn = ilen[n];
    const int L = 2 * tl + 1;
    const int mid = Tn >> 1;
    const int s0 = 4 * lane;

    const int j1 = min(2 * lane, Ss - 1);
    const int j3 = min(2 * lane + 1, Ss - 1);
    const int base = n * Ss;
    const int tg1 = targets[base + j1];
    const int tg3 = targets[base + j3];
    const int tg1m = targets[base + max(2 * lane - 1, 0)];
    const int tg3p = targets[base + min(2 * lane + 2, Ss - 1)];

    const float sk1f = ((s0 + 1 >= 3) && (tg1 != tg1m)) ? 1.f : 0.f;
    const float sk3f = (tg3 != tg1) ? 1.f : 0.f;
    const float sk1b = ((s0 + 3 < L) && (tg3 != tg1)) ? 1.f : 0.f;
    const float sk3b = ((s0 + 5 < L) && (tg3p != tg3)) ? 1.f : 0.f;

    const float* __restrict__ rB = PR + (size_t)(n * Cc) * Tt;
    const float* __restrict__ r1 = PR + (size_t)(n * Cc + tg1) * Tt;
    const float* __restrict__ r3 = PR + (size_t)(n * Cc + tg3) * Tt;
    const float* __restrict__ rD = d2 + (size_t)n * Tt;

    // ---- fwd init ----
    float f0, f1, f2v, f3; int EF = 0;
    {
        float pB0, p10;
        if constexpr (PRE) { pB0 = rB[0]; p10 = r1[0]; }
        else {
            const float dv = rD[0];
            pB0 = exp2_hw(fmaf(rB[0], IL2f, -dv));
            p10 = exp2_hw(fmaf(r1[0], IL2f, -dv));
        }
        f0 = (lane == 0) ? pB0 : 0.f;
        f1 = (lane == 0) ? p10 : 0.f;
        f2v = 0.f; f3 = 0.f;
    }
    // ---- bwd init ----
    float b0, b1, b2, b3; int EB = 0;
    {
        const int te = Tn - 1;
        float pBe, p1e, p3e;
        if constexpr (PRE) { pBe = rB[te]; p1e = r1[te]; p3e = r3[te]; }
        else {
            const float dv = rD[te];
            pBe = exp2_hw(fmaf(rB[te], IL2f, -dv));
            p1e = exp2_hw(fmaf(r1[te], IL2f, -dv));
            p3e = exp2_hw(fmaf(r3[te], IL2f, -dv));
        }
        const int sl = 2 * tl;
        b0 = (s0 == sl) ? pBe : 0.f;
        b1 = (s0 + 1 == sl - 1) ? p1e : 0.f;
        b2 = (s0 + 2 == sl) ? pBe : 0.f;
        b3 = (s0 + 3 == sl - 1) ? p3e : 0.f;
    }

    const int tBF = mid;                        // fwd: t = 1..tBF
    const int gFhi = tBF >> 5;
    const int tAB = mid + 1, tBB = Tn - 2;      // bwd: t = tBB..tAB desc
    const int gBhi = tBB >> 5, gBlo = tAB >> 5;
    const int nIter = max(gFhi + 1, gBhi - gBlo + 1);

    #define ISSUE_D(dir, gg, sl, ra, rb_, rc, rd_) {                                \
        const int bo_ = (gg) * 32;                                                  \
        _Pragma("unroll")                                                           \
        for (int j = 0; j < 8; ++j) {                                               \
            gload16((ra) + bo_ + 4 * j, &lds[dir][sl][0][j][0][0]);                 \
            gload16((rb_) + bo_ + 4 * j, &lds[dir][sl][1][j][0][0]);                \
            gload16((rc) + bo_ + 4 * j, &lds[dir][sl][2][j][0][0]);                 \
            if constexpr (!PRE) gload16((rd_) + bo_ + 4 * j, &lds[dir][sl][NA-1][j][0][0]); \
        }                                                                           \
    }
    #define ISSUE_F(gg, sl) ISSUE_D(0, gg, sl, rB, r1, r3, rD)
    #define ISSUE_B(gg, sl) ISSUE_D(1, gg, sl, rB, r1, r3, rD)
    #define WAIT24() asm volatile("s_waitcnt vmcnt(24)" ::: "memory")
    #define WAIT0()  asm volatile("s_waitcnt vmcnt(0)" ::: "memory")

    // Guarded sequential bodies (boundary groups / !PRE).
    #define BODY_F_G(gg, cs) {                                                      \
        f4 vB[8], vU[8], vW[8], vD[8];                                              \
        _Pragma("unroll")                                                           \
        for (int j = 0; j < 8; ++j) {                                               \
            vB[j] = LD4(&lds[0][cs][0][j][lane][0]);                                \
            vU[j] = LD4(&lds[0][cs][1][j][lane][0]);                                \
            vW[j] = LD4(&lds[0][cs][2][j][lane][0]);                                \
            if constexpr (!PRE) vD[j] = LD4(&lds[0][cs][NA-1][j][lane][0]);         \
        }                                                                           \
        (void)vD;                                                                   \
        _Pragma("unroll")                                                           \
        for (int w = 0; w < 4; ++w) {                                               \
            const int Eu = wave_shr1_i(EF);                                         \
            const int eb = min(max(127 + (Eu - EF), 0), 230);                       \
            const float sc = __int_as_float((unsigned)eb << 23);                    \
            const float sk1fs = sk1f * sc;                                          \
            _Pragma("unroll")                                                       \
            for (int kk = 0; kk < 8; ++kk) {                                        \
                const int k = w * 8 + kk;                                           \
                const int t = (gg) * 32 + k;                                        \
                if (t >= 1 && t <= tBF) {                                           \
                    float pB, p1, p3;                                               \
                    if constexpr (PRE) {                                            \
                        pB = vB[k >> 2][k & 3]; p1 = vU[k >> 2][k & 3];             \
                        p3 = vW[k >> 2][k & 3];                                     \
                    } else {                                                        \
                        const float dv = vD[k >> 2][k & 3];                         \
                        pB = exp2_hw(fmaf(vB[k >> 2][k & 3], IL2f, -dv));           \
                        p1 = exp2_hw(fmaf(vU[k >> 2][k & 3], IL2f, -dv));           \
                        p3 = exp2_hw(fmaf(vW[k >> 2][k & 3], IL2f, -dv));           \
                    }                                                               \
                    const float u3 = wave_shr1(f3);                                 \
                    const float n3 = fmaf(f1, sk3f, f3 + f2v) * p3;                 \
                    const float n2 = (f2v + f1) * pB;                               \
                    const float n1 = fmaf(u3, sk1fs, f1 + f0) * p1;                 \
                    const float n0 = fmaf(u3, sc, f0) * pB;                         \
                    f0 = n0; f1 = n1; f2v = n2; f3 = n3;                            \
                }                                                                   \
            }                                                                       \
            const float mx = fmaxf(fmaxf(f0, f1), fmaxf(f2v, f3));                  \
            const int me = (int)(__float_as_uint(mx) >> 23);                        \
            const float s2 = __int_as_float((unsigned)(254 - me) << 23);            \
            f0 *= s2; f1 *= s2; f2v *= s2; f3 *= s2;                                \
            EF = (mx > 0.f) ? (EF + me - 127) : Eu;                                 \
        }                                                                           \
    }

    #define BODY_B_G(gg, cs) {                                                      \
        f4 vB[8], vU[8], vW[8], vD[8];                                              \
        _Pragma("unroll")                                                           \
        for (int j = 0; j < 8; ++j) {                                               \
            vB[j] = LD4(&lds[1][cs][0][j][lane][0]);                                \
            vU[j] = LD4(&lds[1][cs][1][j][lane][0]);                                \
            vW[j] = LD4(&lds[1][cs][2][j][lane][0]);                                \
            if constexpr (!PRE) vD[j] = LD4(&lds[1][cs][NA-1][j][lane][0]);         \
        }                                                                           \
        (void)vD;                                                                   \
        _Pragma("unroll")                                                           \
        for (int w = 3; w >= 0; --w) {                                              \
            const int Ed = wave_shl1_i(EB);                                         \
            const int eb = min(max(127 + (Ed - EB), 0), 230);                       \
            const float sc = __int_as_float((unsigned)eb << 23);                    \
            const float sk3bs = sk3b * sc;                                          \
            _Pragma("unroll")                                                       \
            for (int kk = 7; kk >= 0; --kk) {                                       \
                const int k = w * 8 + kk;                                           \
                const int t = (gg) * 32 + k;                                        \
                if (t >= tAB && t <= tBB) {                                         \
                    float pB, p1, p3;                                               \
                    if constexpr (PRE) {                                            \
                        pB = vB[k >> 2][k & 3]; p1 = vU[k >> 2][k & 3];             \
                        p3 = vW[k >> 2][k & 3];                                     \
                    } else {                                                        \
                        const float dv = vD[k >> 2][k & 3];                         \
                        pB = exp2_hw(fmaf(vB[k >> 2][k & 3], IL2f, -dv));           \
                        p1 = exp2_hw(fmaf(vU[k >> 2][k & 3], IL2f, -dv));           \
                        p3 = exp2_hw(fmaf(vW[k >> 2][k & 3], IL2f, -dv));           \
                    }                                                               \
                    const float d0 = wave_shl1(b0);                                 \
                    const float d1 = wave_shl1(b1);                                 \
                    const float n0 = (b0 + b1) * pB;                                \
                    const float n1 = fmaf(b3, sk1b, b1 + b2) * p1;                  \
                    const float n2 = (b2 + b3) * pB;                                \
                    const float n3 = fmaf(d1, sk3bs, fmaf(d0, sc, b3)) * p3;        \
                    b0 = n0; b1 = n1; b2 = n2; b3 = n3;                             \
                }                                                                   \
            }                                                                       \
            const float mx = fmaxf(fmaxf(b0, b1), fmaxf(b2, b3));                   \
            const int me = (int)(__float_as_uint(mx) >> 23);                        \
            const float s2 = __int_as_float((unsigned)(254 - me) << 23);            \
            b0 *= s2; b1 *= s2; b2 *= s2; b3 *= s2;                                 \
            EB = (mx > 0.f) ? (EB + me - 127) : Ed;                                 \
        }                                                                           \
    }

    // Interleaved packed body (full groups, PRE only): F window w with B window
    // 3-w, step pairs interleaved so the two chains fill each other's stalls.
    #define BODY_FB_P(cs) {                                                         \
        f2 QF0 = {f0, f2v}, QF1 = {f1, f3};                                         \
        f2 QB0 = {b0, b2},  QB1 = {b1, b3};                                         \
        _Pragma("unroll")                                                           \
        for (int w = 0; w < 4; ++w) {                                               \
            const int wb = 3 - w;                                                   \
            const int EuF = wave_shr1_i(EF);                                        \
            const int ebF = min(max(127 + (EuF - EF), 0), 230);                     \
            const float scF = __int_as_float((unsigned)ebF << 23);                  \
            const f2 KskF = {sk3f, sk1f * scF};                                     \
            const f2 K1sF = {1.0f, scF};                                            \
            const int EdB = wave_shl1_i(EB);                                        \
            const int ebB = min(max(127 + (EdB - EB), 0), 230);                     \
            const float scB = __int_as_float((unsigned)ebB << 23);                  \
            const f2 K1sB = {1.0f, scB};                                            \
            const f2 KskB = {sk1b, sk3b * scB};                                     \
            f4 fB0 = LD4(&lds[0][cs][0][2*w][lane][0]);                             \
            f4 fB1 = LD4(&lds[0][cs][0][2*w+1][lane][0]);                           \
            f4 fU0 = LD4(&lds[0][cs][1][2*w][lane][0]);                             \
            f4 fU1 = LD4(&lds[0][cs][1][2*w+1][lane][0]);                           \
            f4 fW0 = LD4(&lds[0][cs][2][2*w][lane][0]);                             \
            f4 fW1 = LD4(&lds[0][cs][2][2*w+1][lane][0]);                           \
            f4 xB0 = LD4(&lds[1][cs][0][2*wb][lane][0]);                            \
            f4 xB1 = LD4(&lds[1][cs][0][2*wb+1][lane][0]);                          \
            f4 xU0 = LD4(&lds[1][cs][1][2*wb][lane][0]);                            \
            f4 xU1 = LD4(&lds[1][cs][1][2*wb+1][lane][0]);                          \
            f4 xW0 = LD4(&lds[1][cs][2][2*wb][lane][0]);                            \
            f4 xW1 = LD4(&lds[1][cs][2][2*wb+1][lane][0]);                          \
            _Pragma("unroll")                                                       \
            for (int kk = 0; kk < 8; ++kk) {                                        \
                /* ---- F step k = w*8+kk (ascending) ---- */                       \
                {                                                                   \
                    const float pB = (kk < 4 ? fB0 : fB1)[kk & 3];                  \
                    const f2 P31 = {(kk < 4 ? fW0 : fW1)[kk & 3],                   \
                                    (kk < 4 ? fU0 : fU1)[kk & 3]};                  \
                    const f2 PBB = {pB, pB};                                        \
                    const float u3 = wave_shr1(QF1.y);                              \
                    const f2 M = {QF1.x, u3};                                       \
                    const f2 Q0s = __builtin_shufflevector(QF0, QF0, 1, 0);         \
                    const f2 S = __builtin_shufflevector(QF1, QF1, 1, 0) + Q0s;     \
                    const f2 Fv = __builtin_elementwise_fma(M, KskF, S);            \
                    const f2 G = __builtin_elementwise_fma(M, K1sF, Q0s);           \
                    const f2 N31 = Fv * P31;                                        \
                    const f2 N20 = G * PBB;                                         \
                    QF1 = __builtin_shufflevector(N31, N31, 1, 0);                  \
                    QF0 = __builtin_shufflevector(N20, N20, 1, 0);                  \
                }                                                                   \
                /* ---- B step k = wb*8+(7-kk) (descending) ---- */                 \
                {                                                                   \
                    const int kb = 7 - kk;                                          \
                    const float pB = (kk < 4 ? xB1 : xB0)[kb & 3];                  \
                    const f2 P13 = {(kk < 4 ? xU1 : xU0)[kb & 3],                   \
                                    (kk < 4 ? xW1 : xW0)[kb & 3]};                  \
                    const f2 PBB = {pB, pB};                                        \
                    const float d0 = wave_shl1(QB0.x);                              \
                    const float d1 = wave_shl1(QB1.x);                              \
                    const f2 S = QB0 + QB1;                                         \
                    const f2 A2 = __builtin_elementwise_fma((f2){QB0.y, d0}, K1sB, QB1); \
                    const f2 B2 = __builtin_elementwise_fma((f2){QB1.y, d1}, KskB, A2);  \
                    QB1 = B2 * P13;                                                 \
                    QB0 = S * PBB;                                                  \
                }                                                                   \
            }                                                                       \
            {                                                                       \
                const f2 mxv = __builtin_elementwise_max(QF0, QF1);                 \
                const float mx = fmaxf(mxv.x, mxv.y);                               \
                const int me = (int)(__float_as_uint(mx) >> 23);                    \
                const float s2 = __int_as_float((unsigned)(254 - me) << 23);        \
                const f2 S2 = {s2, s2};                                             \
                QF0 *= S2; QF1 *= S2;                                               \
                EF = (mx > 0.f) ? (EF + me - 127) : EuF;                            \
            }                                                                       \
            {                                                                       \
                const f2 mxv = __builtin_elementwise_max(QB0, QB1);                 \
                const float mx = fmaxf(mxv.x, mxv.y);                               \
                const int me = (int)(__float_as_uint(mx) >> 23);                    \
                const float s2 = __int_as_float((unsigned)(254 - me) << 23);        \
                const f2 S2 = {s2, s2};                                             \
                QB0 *= S2; QB1 *= S2;                                               \
                EB = (mx > 0.f) ? (EB + me - 127) : EdB;                            \
            }                                                                       \
        }                                                                           \
        f0 = QF0.x; f2v = QF0.y; f1 = QF1.x; f3 = QF1.y;                            \
        b0 = QB0.x; b2 = QB0.y;  b1 = QB1.x; b3 = QB1.y;                            \
    }

    if constexpr (PRE) {
        ISSUE_F(0, 0);
        ISSUE_B(gBhi, 0);
        int cur = 0;
        for (int i = 0; i < nIter; ++i) {
            const int gf = min(i, gFhi);
            const int gb = max(gBhi - i, gBlo);
            const bool fAct = (i <= gFhi);
            const bool bAct = (gBhi - i >= gBlo);
            WAIT24();                                   // F(i) landed
            ISSUE_F(min(gf + 1, gFhi), cur ^ 1);
            WAIT24();                                   // B(i) landed
            ISSUE_B(max(gb - 1, gBlo), cur ^ 1);
            const bool fFull = fAct && gf >= 1 && gf * 32 + 31 <= tBF;
            const bool bFull = bAct && gb * 32 >= tAB && gb * 32 + 31 <= tBB;
            if (fFull && bFull) { BODY_FB_P(cur); }
            else {
                if (fAct) BODY_F_G(gf, cur);
                if (bAct) BODY_B_G(gb, cur);
            }
            cur ^= 1;
        }
    } else {
        // fallback: serial issue/wait (workspace too small for P)
        int cur = 0;
        for (int i = 0; i < nIter; ++i) {
            const int gf = min(i, gFhi);
            const int gb = max(gBhi - i, gBlo);
            const bool fAct = (i <= gFhi);
            const bool bAct = (gBhi - i >= gBlo);
            ISSUE_F(gf, cur);
            ISSUE_B(gb, cur);
            WAIT0();
            if (fAct) BODY_F_G(gf, cur);
            if (bAct) BODY_B_G(gb, cur);
            cur ^= 1;
        }
    }
    #undef ISSUE_D
    #undef ISSUE_F
    #undef ISSUE_B
    #undef WAIT24
    #undef WAIT0
    #undef BODY_F_G
    #undef BODY_B_G
    #undef BODY_FB_P

    // convert to log2 domain for the combine kernel
    {
        float* dst = wsA + n * 256;
        const float Ef = (float)EF;
        f4 o;
        o[0] = (s0     < L && f0  > 0.f) ? log2_hw(f0)  + Ef : NEGV;
        o[1] = (s0 + 1 < L && f1  > 0.f) ? log2_hw(f1)  + Ef : NEGV;
        o[2] = (s0 + 2 < L && f2v > 0.f) ? log2_hw(f2v) + Ef : NEGV;
        o[3] = (s0 + 3 < L && f3  > 0.f) ? log2_hw(f3)  + Ef : NEGV;
        *(f4*)(dst + s0) = o;
    }
    {
        float* dst = wsB + n * 256;
        const float Eb = (float)EB;
        f4 o;
        o[0] = (s0     < L && b0 > 0.f) ? log2_hw(b0) + Eb : NEGV;
        o[1] = (s0 + 1 < L && b1 > 0.f) ? log2_hw(b1) + Eb : NEGV;
        o[2] = (s0 + 2 < L && b2 > 0.f) ? log2_hw(b2) + Eb : NEGV;
        o[3] = (s0 + 3 < L && b3 > 0.f) ? log2_hw(b3) + Eb : NEGV;
        *(f4*)(dst + s0) = o;
    }
}

// ---------------- Kernel 3: splice alpha*beta, lse over states, mean ----------------
__global__ __launch_bounds__(64) void ctc_combine_kernel(
    const float* __restrict__ wsA, const float* __restrict__ wsB,
    const int* __restrict__ targets, const int* __restrict__ tlen,
    float* __restrict__ out)
{
    const int n = blockIdx.x;
    const int lane = threadIdx.x;
    const int tl = tlen[n];
    const int L = 2 * tl + 1;
    float vals[4];
    float vmax = NEGV;
    #pragma unroll
    for (int k = 0; k < 4; ++k) {
        const int s = lane + (k << 6);
        float v = NEGV;
        if (s < L) {
            const float al = wsA[n * 256 + s];
            const float b0 = wsB[n * 256 + s];
            const float b1 = (s + 1 < L) ? wsB[n * 256 + s + 1] : NEGV;
            const bool skip = (s & 1) && (s + 2 < L) &&
                (targets[n * Ss + (s >> 1) + 1] != targets[n * Ss + (s >> 1)]);
            const float b2 = skip ? wsB[n * 256 + s + 2] : NEGV;
            const float m3 = fmaxf(fmaxf(b0, b1), b2);
            const float B = m3 + log2_hw(exp2_hw(b0 - m3) + exp2_hw(b1 - m3) + exp2_hw(b2 - m3));
            v = al + B;
        }
        vals[k] = v;
        vmax = fmaxf(vmax, v);
    }
    #pragma unroll
    for (int o = 32; o; o >>= 1) vmax = fmaxf(vmax, __shfl_xor(vmax, o));
    float ssum = 0.f;
    #pragma unroll
    for (int k = 0; k < 4; ++k) ssum += exp2_hw(vals[k] - vmax);
    #pragma unroll
    for (int o = 32; o; o >>= 1) ssum += __shfl_xor(ssum, o);
    if (lane == 0) {
        const float total2 = vmax + log2_hw(ssum);
        const float loss = -LN2f * total2;
        atomicAdd(out, loss / ((float)tl * (float)Nn));
    }
}

extern "C" void kernel_launch(void* const* d_in, const int* in_sizes, int n_in,
                              void* d_out, int out_size, void* d_ws, size_t ws_size,
                              hipStream_t stream) {
    const float* logits = (const float*)d_in[0];
    const int* targets  = (const int*)d_in[1];
    const int* tlen     = (const int*)d_in[2];
    const int* ilen     = (const int*)d_in[3];
    float* out = (float*)d_out;

    float* wsA = (float*)d_ws;                     // 64*256
    float* wsB = wsA + Nn * 256;                   // 64*256
    float* d2  = wsB + Nn * 256;                   // 64*4000
    float* P   = d2 + (size_t)Nn * Tt;             // 64*64*4000 (if it fits)
    const size_t need = ((size_t)Nn * 256 * 2 + (size_t)Nn * Tt
                         + (size_t)Nn * Cc * Tt) * sizeof(float);
    const bool pre = (ws_size >= need);

    hipMemsetAsync(d_out, 0, sizeof(float), stream);
    ctc_denom_kernel<<<dim3(4, Nn), 256, 0, stream>>>(logits, d2);
    if (pre) {
        ctc_prob_kernel<<<dim3(4, Nn, 8), 256, 0, stream>>>(logits, d2, P);
        ctc_fb_kernel<true><<<Nn, 64, 0, stream>>>(P, targets, tlen, ilen, d2, wsA, wsB);
    } else {
        ctc_fb_kernel<false><<<Nn, 64, 0, stream>>>(logits, targets, tlen, ilen, d2, wsA, wsB);
    }
    ctc_combine_kernel<<<Nn, 64, 0, stream>>>(wsA, wsB, targets, tlen, out);
}

// Round 14
// 107.809 us; speedup vs baseline: 1.7558x; 1.7558x over previous
//
#include <hip/hip_runtime.h>
#include <cstdint>
#include <cstddef>

#define NEGV (-1e30f)
#define IL2f 1.44269504088896340736f
#define LN2f 0.693147180559945309417f

__device__ __forceinline__ float exp2_hw(float x) { return __builtin_amdgcn_exp2f(x); }
__device__ __forceinline__ float log2_hw(float x) { return __builtin_amdgcn_logf(x); }

constexpr int Nn = 64, Cc = 64, Tt = 4000, Ss = 100;

__device__ __forceinline__ float wave_shr1(float x) {  // lane n <- lane n-1
    return __int_as_float(__builtin_amdgcn_update_dpp(0, __float_as_int(x), 0x138, 0xF, 0xF, true));
}
__device__ __forceinline__ float wave_shl1(float x) {  // lane n <- lane n+1
    return __int_as_float(__builtin_amdgcn_update_dpp(0, __float_as_int(x), 0x130, 0xF, 0xF, true));
}
__device__ __forceinline__ int wave_shr1_i(int x) {
    return __builtin_amdgcn_update_dpp(0, x, 0x138, 0xF, 0xF, true);
}
__device__ __forceinline__ int wave_shl1_i(int x) {
    return __builtin_amdgcn_update_dpp(0, x, 0x130, 0xF, 0xF, true);
}

typedef float f4 __attribute__((ext_vector_type(4)));
typedef float f2 __attribute__((ext_vector_type(2)));
#define LD4(p) (*(const f4*)(p))

__device__ __forceinline__ void gload16(const float* g, float* l) {
    __builtin_amdgcn_global_load_lds(
        (const __attribute__((address_space(1))) void*)g,
        (__attribute__((address_space(3))) void*)l, 16, 0, 0);
}

// ------- Kernel 1a: PARTIAL log2-softmax denominator (z splits C in halves) -------
__global__ __launch_bounds__(256) void ctc_denom_part(
    const float* __restrict__ logits, float* __restrict__ dP)
{
    const int t4 = (blockIdx.x * 256 + threadIdx.x) * 4;
    const int n = blockIdx.y;
    const int c0 = blockIdx.z * 32;
    if (t4 >= Tt) return;
    const float* __restrict__ p = logits + ((size_t)(n * Cc + c0)) * Tt + t4;
    f4 m, s;
    {
        f4 v = LD4(p);
        #pragma unroll
        for (int i = 0; i < 4; ++i) { m[i] = v[i] * IL2f; s[i] = 1.f; }
    }
    #pragma unroll 4
    for (int c = 1; c < 32; ++c) {
        f4 v = LD4(p + (size_t)c * Tt);
        #pragma unroll
        for (int i = 0; i < 4; ++i) {
            float vi = v[i] * IL2f;
            float nm = fmaxf(m[i], vi);
            s[i] = s[i] * exp2_hw(m[i] - nm) + exp2_hw(vi - nm);
            m[i] = nm;
        }
    }
    f4 o;
    #pragma unroll
    for (int i = 0; i < 4; ++i) o[i] = m[i] + log2_hw(s[i]);
    *(f4*)(dP + ((size_t)blockIdx.z * Nn + n) * Tt + t4) = o;
}

// ------- Kernel 1a' (tier2): full denominator in one pass -------
__global__ __launch_bounds__(256) void ctc_denom_kernel(
    const float* __restrict__ logits, float* __restrict__ d2)
{
    const int t4 = (blockIdx.x * 256 + threadIdx.x) * 4;
    const int n = blockIdx.y;
    if (t4 >= Tt) return;
    const float* __restrict__ p = logits + (size_t)n * Cc * Tt + t4;
    f4 m, s;
    {
        f4 v = LD4(p);
        #pragma unroll
        for (int i = 0; i < 4; ++i) { m[i] = v[i] * IL2f; s[i] = 1.f; }
    }
    #pragma unroll 4
    for (int c = 1; c < Cc; ++c) {
        f4 v = LD4(p + (size_t)c * Tt);
        #pragma unroll
        for (int i = 0; i < 4; ++i) {
            float vi = v[i] * IL2f;
            float nm = fmaxf(m[i], vi);
            s[i] = s[i] * exp2_hw(m[i] - nm) + exp2_hw(vi - nm);
            m[i] = nm;
        }
    }
    f4 o;
    #pragma unroll
    for (int i = 0; i < 4; ++i) o[i] = m[i] + log2_hw(s[i]);
    *(f4*)(d2 + (size_t)n * Tt + t4) = o;
}

// ------- Kernel 1c (tier3): merge partials into d2 (in-place into dP half 0) -------
__global__ __launch_bounds__(256) void ctc_denom_merge(float* __restrict__ dP)
{
    const int t4 = (blockIdx.x * 256 + threadIdx.x) * 4;
    const int n = blockIdx.y;
    if (t4 >= Tt) return;
    f4 a = LD4(dP + (size_t)n * Tt + t4);
    f4 b = LD4(dP + ((size_t)Nn + n) * Tt + t4);
    f4 d;
    #pragma unroll
    for (int i = 0; i < 4; ++i) {
        const float mm = fmaxf(a[i], b[i]);
        d[i] = mm + log2_hw(exp2_hw(a[i] - mm) + exp2_hw(b[i] - mm));
    }
    *(f4*)(dP + (size_t)n * Tt + t4) = d;
}

// ------- Kernel 1b: membership-filtered probabilities -------
// Only classes in {blank} ∪ targets[n][0..tl) are ever read by fb; skip the rest
// (no read, no write). Stale P rows only multiply zero-valued invalid-lane states.
template<bool MERGE>
__global__ __launch_bounds__(256) void ctc_prob_sel(
    const float* __restrict__ logits, const float* __restrict__ dP,
    const int* __restrict__ targets, const int* __restrict__ tlen,
    float* __restrict__ P)
{
    const int n = blockIdx.y;
    const int c0 = blockIdx.z * 8;
    __shared__ int needs;
    if (threadIdx.x == 0) needs = (c0 == 0) ? 1 : 0;   // blank always needed
    __syncthreads();
    const int tl = tlen[n];
    if ((int)threadIdx.x < min(tl, Ss)) {
        const int rel = targets[n * Ss + threadIdx.x] - c0;
        if (rel >= 0 && rel < 8) atomicOr(&needs, 1 << rel);
    }
    __syncthreads();
    const int nd = needs;
    if (nd == 0) return;
    const int t4 = (blockIdx.x * 256 + threadIdx.x) * 4;
    if (t4 >= Tt) return;
    f4 d;
    if constexpr (MERGE) {
        f4 a = LD4(dP + (size_t)n * Tt + t4);
        f4 b = LD4(dP + ((size_t)Nn + n) * Tt + t4);
        #pragma unroll
        for (int i = 0; i < 4; ++i) {
            const float mm = fmaxf(a[i], b[i]);
            d[i] = mm + log2_hw(exp2_hw(a[i] - mm) + exp2_hw(b[i] - mm));
        }
    } else {
        d = LD4(dP + (size_t)n * Tt + t4);
    }
    const float* __restrict__ src = logits + ((size_t)(n * Cc + c0)) * Tt + t4;
    float* __restrict__ dst = P + ((size_t)(n * Cc + c0)) * Tt + t4;
    #pragma unroll
    for (int c = 0; c < 8; ++c) {
        if ((nd >> c) & 1) {
            f4 v = LD4(src + (size_t)c * Tt);
            f4 o;
            #pragma unroll
            for (int i = 0; i < 4; ++i) o[i] = exp2_hw(fmaf(v[i], IL2f, -d[i]));
            *(f4*)(dst + (size_t)c * Tt) = o;
        }
    }
}

// ---------------- Kernel 2: fwd/bwd recurrence (EXACT R12 structure, 73us) ----------
template<bool PRE>
__global__ __launch_bounds__(64) void ctc_fb_kernel(
    const float* __restrict__ PR, const int* __restrict__ targets,
    const int* __restrict__ tlen, const int* __restrict__ ilen,
    const float* __restrict__ d2, float* __restrict__ wsA, float* __restrict__ wsB)
{
    constexpr int NA = PRE ? 3 : 4;
    constexpr int NLD = NA * 8;
    __shared__ float lds[2][NA][8][64][4];

    const int bid = blockIdx.x;
    const int n = bid >> 1;
    const bool bwd = bid & 1;
    const int lane = threadIdx.x;
    const int tl = tlen[n];
    const int Tn = ilen[n];
    const int L = 2 * tl + 1;
    const int mid = Tn >> 1;
    const int s0 = 4 * lane;

    const int j1 = min(2 * lane, Ss - 1);
    const int j3 = min(2 * lane + 1, Ss - 1);
    const int base = n * Ss;
    const int tg1 = targets[base + j1];
    const int tg3 = targets[base + j3];
    const int tg1m = targets[base + max(2 * lane - 1, 0)];
    const int tg3p = targets[base + min(2 * lane + 2, Ss - 1)];

    const float sk1f = ((s0 + 1 >= 3) && (tg1 != tg1m)) ? 1.f : 0.f;
    const float sk3f = (tg3 != tg1) ? 1.f : 0.f;
    const float sk1b = ((s0 + 3 < L) && (tg3 != tg1)) ? 1.f : 0.f;
    const float sk3b = ((s0 + 5 < L) && (tg3p != tg3)) ? 1.f : 0.f;

    const float* __restrict__ rB = PR + (size_t)(n * Cc) * Tt;
    const float* __restrict__ r1 = PR + (size_t)(n * Cc + tg1) * Tt;
    const float* __restrict__ r3 = PR + (size_t)(n * Cc + tg3) * Tt;
    const float* __restrict__ rD = d2 + (size_t)n * Tt;

    float a0, a1, a2, a3;
    int E = 0;

    if (!bwd) {
        float pB0, p10;
        if constexpr (PRE) { pB0 = rB[0]; p10 = r1[0]; }
        else {
            const float dv = rD[0];
            pB0 = exp2_hw(fmaf(rB[0], IL2f, -dv));
            p10 = exp2_hw(fmaf(r1[0], IL2f, -dv));
        }
        a0 = (lane == 0) ? pB0 : 0.f;
        a1 = (lane == 0) ? p10 : 0.f;
        a2 = 0.f; a3 = 0.f;
    } else {
        const int te = Tn - 1;
        float pBe, p1e, p3e;
        if constexpr (PRE) { pBe = rB[te]; p1e = r1[te]; p3e = r3[te]; }
        else {
            const float dv = rD[te];
            pBe = exp2_hw(fmaf(rB[te], IL2f, -dv));
            p1e = exp2_hw(fmaf(r1[te], IL2f, -dv));
            p3e = exp2_hw(fmaf(r3[te], IL2f, -dv));
        }
        const int sl = 2 * tl;
        a0 = (s0 == sl) ? pBe : 0.f;
        a1 = (s0 + 1 == sl - 1) ? p1e : 0.f;
        a2 = (s0 + 2 == sl) ? pBe : 0.f;
        a3 = (s0 + 3 == sl - 1) ? p3e : 0.f;
    }

    #define ISSUE(gg, sl) {                                                         \
        const int bo_ = (gg) * 32;                                                  \
        _Pragma("unroll")                                                           \
        for (int j = 0; j < 8; ++j) {                                               \
            gload16(rB + bo_ + 4 * j, &lds[sl][0][j][0][0]);                        \
            gload16(r1 + bo_ + 4 * j, &lds[sl][1][j][0][0]);                        \
            gload16(r3 + bo_ + 4 * j, &lds[sl][2][j][0][0]);                        \
            if constexpr (!PRE) gload16(rD + bo_ + 4 * j, &lds[sl][NA - 1][j][0][0]); \
        }                                                                           \
    }
    #define WAITG() asm volatile("s_waitcnt vmcnt(%0)" :: "n"(NLD) : "memory")
    #define LOADREGS(slc)                                                           \
        f4 vB[8], vU[8], vW[8], vD[8];                                              \
        _Pragma("unroll")                                                           \
        for (int j = 0; j < 8; ++j) {                                               \
            vB[j] = LD4(&lds[slc][0][j][lane][0]);                                  \
            vU[j] = LD4(&lds[slc][1][j][lane][0]);                                  \
            vW[j] = LD4(&lds[slc][2][j][lane][0]);                                  \
            if constexpr (!PRE) vD[j] = LD4(&lds[slc][NA - 1][j][lane][0]);         \
        }                                                                           \
        (void)vD;

    #define RENORM_S(nb) {                                                          \
        const float mx = fmaxf(fmaxf(a0, a1), fmaxf(a2, a3));                       \
        const int me = (int)(__float_as_uint(mx) >> 23);                            \
        const float s2 = __int_as_float((unsigned)(254 - me) << 23);                \
        a0 *= s2; a1 *= s2; a2 *= s2; a3 *= s2;                                     \
        E = (mx > 0.f) ? (E + me - 127) : (nb);                                     \
    }

    if (!bwd) {
        const int tB = mid;
        const int gHi = tB >> 5;

        #define BODY_F_G(gg) {                                                      \
            _Pragma("unroll")                                                       \
            for (int w = 0; w < 4; ++w) {                                           \
                const int Eu = wave_shr1_i(E);                                      \
                const int eb = min(max(127 + (Eu - E), 0), 230);                    \
                const float sc = __int_as_float((unsigned)eb << 23);                \
                const float sk1fs = sk1f * sc;                                      \
                _Pragma("unroll")                                                   \
                for (int kk = 0; kk < 8; ++kk) {                                    \
                    const int k = w * 8 + kk;                                       \
                    const int t = (gg) * 32 + k;                                    \
                    if (t >= 1 && t <= tB) {                                        \
                        float pB, p1, p3;                                           \
                        if constexpr (PRE) {                                        \
                            pB = vB[k >> 2][k & 3]; p1 = vU[k >> 2][k & 3];         \
                            p3 = vW[k >> 2][k & 3];                                 \
                        } else {                                                    \
                            const float dv = vD[k >> 2][k & 3];                     \
                            pB = exp2_hw(fmaf(vB[k >> 2][k & 3], IL2f, -dv));       \
                            p1 = exp2_hw(fmaf(vU[k >> 2][k & 3], IL2f, -dv));       \
                            p3 = exp2_hw(fmaf(vW[k >> 2][k & 3], IL2f, -dv));       \
                        }                                                           \
                        const float u3 = wave_shr1(a3);                             \
                        const float n3 = fmaf(a1, sk3f, a3 + a2) * p3;              \
                        const float n2 = (a2 + a1) * pB;                            \
                        const float n1 = fmaf(u3, sk1fs, a1 + a0) * p1;             \
                        const float n0 = fmaf(u3, sc, a0) * pB;                     \
                        a0 = n0; a1 = n1; a2 = n2; a3 = n3;                         \
                    }                                                               \
                }                                                                   \
                RENORM_S(Eu);                                                       \
            }                                                                       \
        }

        #define BODY_F_F() {                                                        \
            f2 Q0 = {a0, a2}, Q1 = {a1, a3};                                        \
            _Pragma("unroll")                                                       \
            for (int w = 0; w < 4; ++w) {                                           \
                const int Eu = wave_shr1_i(E);                                      \
                const int eb = min(max(127 + (Eu - E), 0), 230);                    \
                const float sc = __int_as_float((unsigned)eb << 23);                \
                const f2 Ksk = {sk3f, sk1f * sc};                                   \
                const f2 K1s = {1.0f, sc};                                          \
                _Pragma("unroll")                                                   \
                for (int kk = 0; kk < 8; ++kk) {                                    \
                    const int k = w * 8 + kk;                                       \
                    const float pB = vB[k >> 2][k & 3];                             \
                    const f2 P31 = {vW[k >> 2][k & 3], vU[k >> 2][k & 3]};          \
                    const f2 PBB = {pB, pB};                                        \
                    const float u3 = wave_shr1(Q1.y);                               \
                    const f2 M = {Q1.x, u3};                                        \
                    const f2 Q0s = __builtin_shufflevector(Q0, Q0, 1, 0);           \
                    const f2 S = __builtin_shufflevector(Q1, Q1, 1, 0) + Q0s;       \
                    const f2 F = __builtin_elementwise_fma(M, Ksk, S);              \
                    const f2 G = __builtin_elementwise_fma(M, K1s, Q0s);            \
                    const f2 N31 = F * P31;                                         \
                    const f2 N20 = G * PBB;                                         \
                    Q1 = __builtin_shufflevector(N31, N31, 1, 0);                   \
                    Q0 = __builtin_shufflevector(N20, N20, 1, 0);                   \
                }                                                                   \
                const f2 mxv = __builtin_elementwise_max(Q0, Q1);                   \
                const float mx = fmaxf(mxv.x, mxv.y);                               \
                const int me = (int)(__float_as_uint(mx) >> 23);                    \
                const float s2 = __int_as_float((unsigned)(254 - me) << 23);        \
                const f2 S2 = {s2, s2};                                             \
                Q0 *= S2; Q1 *= S2;                                                 \
                E = (mx > 0.f) ? (E + me - 127) : Eu;                               \
            }                                                                       \
            a0 = Q0.x; a2 = Q0.y; a1 = Q1.x; a3 = Q1.y;                             \
        }

        ISSUE(0, 0);
        int cur = 0;
        for (int g = 0; g <= gHi; ++g) {
            ISSUE(min(g + 1, gHi), cur ^ 1);
            WAITG();
            LOADREGS(cur);
            cur ^= 1;
            if (PRE && g >= 1 && g * 32 + 31 <= tB) { BODY_F_F(); }
            else                                    { BODY_F_G(g); }
        }
        #undef BODY_F_G
        #undef BODY_F_F
    } else {
        const int tB = Tn - 2, tA = mid + 1;
        const int gHi = tB >> 5, gLo = tA >> 5;

        #define BODY_B_G(gg) {                                                      \
            _Pragma("unroll")                                                       \
            for (int w = 3; w >= 0; --w) {                                          \
                const int Ed = wave_shl1_i(E);                                      \
                const int eb = min(max(127 + (Ed - E), 0), 230);                    \
                const float sc = __int_as_float((unsigned)eb << 23);                \
                const float sk3bs = sk3b * sc;                                      \
                _Pragma("unroll")                                                   \
                for (int kk = 7; kk >= 0; --kk) {                                   \
                    const int k = w * 8 + kk;                                       \
                    const int t = (gg) * 32 + k;                                    \
                    if (t >= tA && t <= tB) {                                       \
                        float pB, p1, p3;                                           \
                        if constexpr (PRE) {                                        \
                            pB = vB[k >> 2][k & 3]; p1 = vU[k >> 2][k & 3];         \
                            p3 = vW[k >> 2][k & 3];                                 \
                        } else {                                                    \
                            const float dv = vD[k >> 2][k & 3];                     \
                            pB = exp2_hw(fmaf(vB[k >> 2][k & 3], IL2f, -dv));       \
                            p1 = exp2_hw(fmaf(vU[k >> 2][k & 3], IL2f, -dv));       \
                            p3 = exp2_hw(fmaf(vW[k >> 2][k & 3], IL2f, -dv));       \
                        }                                                           \
                        const float d0 = wave_shl1(a0);                             \
                        const float d1 = wave_shl1(a1);                             \
                        const float n0 = (a0 + a1) * pB;                            \
                        const float n1 = fmaf(a3, sk1b, a1 + a2) * p1;              \
                        const float n2 = (a2 + a3) * pB;                            \
                        const float n3 = fmaf(d1, sk3bs, fmaf(d0, sc, a3)) * p3;    \
                        a0 = n0; a1 = n1; a2 = n2; a3 = n3;                         \
                    }                                                               \
                }                                                                   \
                RENORM_S(Ed);                                                       \
            }                                                                       \
        }

        #define BODY_B_F() {                                                        \
            f2 Q0 = {a0, a2}, Q1 = {a1, a3};                                        \
            _Pragma("unroll")                                                       \
            for (int w = 3; w >= 0; --w) {                                          \
                const int Ed = wave_shl1_i(E);                                      \
                const int eb = min(max(127 + (Ed - E), 0), 230);                    \
                const float sc = __int_as_float((unsigned)eb << 23);                \
                const f2 K1s = {1.0f, sc};                                          \
                const f2 Ksk = {sk1b, sk3b * sc};                                   \
                _Pragma("unroll")                                                   \
                for (int kk = 7; kk >= 0; --kk) {                                   \
                    const int k = w * 8 + kk;                                       \
                    const float pB = vB[k >> 2][k & 3];                             \
                    const f2 P13 = {vU[k >> 2][k & 3], vW[k >> 2][k & 3]};          \
                    const f2 PBB = {pB, pB};                                        \
                    const float d0 = wave_shl1(Q0.x);                               \
                    const float d1 = wave_shl1(Q1.x);                               \
                    const f2 S = Q0 + Q1;                                           \
                    const f2 A2 = __builtin_elementwise_fma((f2){Q0.y, d0}, K1s, Q1); \
                    const f2 B2 = __builtin_elementwise_fma((f2){Q1.y, d1}, Ksk, A2); \
                    Q1 = B2 * P13;                                                  \
                    Q0 = S * PBB;                                                   \
                }                                                                   \
                const f2 mxv = __builtin_elementwise_max(Q0, Q1);                   \
                const float mx = fmaxf(mxv.x, mxv.y);                               \
                const int me = (int)(__float_as_uint(mx) >> 23);                    \
                const float s2 = __int_as_float((unsigned)(254 - me) << 23);        \
                const f2 S2 = {s2, s2};                                             \
                Q0 *= S2; Q1 *= S2;                                                 \
                E = (mx > 0.f) ? (E + me - 127) : Ed;                               \
            }                                                                       \
            a0 = Q0.x; a2 = Q0.y; a1 = Q1.x; a3 = Q1.y;                             \
        }

        ISSUE(gHi, 0);
        int cur = 0;
        for (int g = gHi; g >= gLo; --g) {
            ISSUE(max(g - 1, 0), cur ^ 1);
            WAITG();
            LOADREGS(cur);
            cur ^= 1;
            if (PRE && g * 32 >= tA && g * 32 + 31 <= tB) { BODY_B_F(); }
            else                                          { BODY_B_G(g); }
        }
        #undef BODY_B_G
        #undef BODY_B_F
    }
    #undef ISSUE
    #undef WAITG
    #undef LOADREGS
    #undef RENORM_S

    float* dst = (bwd ? wsB : wsA) + n * 256;
    const float Ef = (float)E;
    f4 o;
    o[0] = (s0     < L && a0 > 0.f) ? log2_hw(a0) + Ef : NEGV;
    o[1] = (s0 + 1 < L && a1 > 0.f) ? log2_hw(a1) + Ef : NEGV;
    o[2] = (s0 + 2 < L && a2 > 0.f) ? log2_hw(a2) + Ef : NEGV;
    o[3] = (s0 + 3 < L && a3 > 0.f) ? log2_hw(a3) + Ef : NEGV;
    *(f4*)(dst + s0) = o;
}

// ---------------- Kernel 3: splice alpha*beta, lse over states, mean ----------------
__global__ __launch_bounds__(64) void ctc_combine_kernel(
    const float* __restrict__ wsA, const float* __restrict__ wsB,
    const int* __restrict__ targets, const int* __restrict__ tlen,
    float* __restrict__ out)
{
    const int n = blockIdx.x;
    const int lane = threadIdx.x;
    const int tl = tlen[n];
    const int L = 2 * tl + 1;
    float vals[4];
    float vmax = NEGV;
    #pragma unroll
    for (int k = 0; k < 4; ++k) {
        const int s = lane + (k << 6);
        float v = NEGV;
        if (s < L) {
            const float al = wsA[n * 256 + s];
            const float b0 = wsB[n * 256 + s];
            const float b1 = (s + 1 < L) ? wsB[n * 256 + s + 1] : NEGV;
            const bool skip = (s & 1) && (s + 2 < L) &&
                (targets[n * Ss + (s >> 1) + 1] != targets[n * Ss + (s >> 1)]);
            const float b2 = skip ? wsB[n * 256 + s + 2] : NEGV;
            const float m3 = fmaxf(fmaxf(b0, b1), b2);
            const float B = m3 + log2_hw(exp2_hw(b0 - m3) + exp2_hw(b1 - m3) + exp2_hw(b2 - m3));
            v = al + B;
        }
        vals[k] = v;
        vmax = fmaxf(vmax, v);
    }
    #pragma unroll
    for (int o = 32; o; o >>= 1) vmax = fmaxf(vmax, __shfl_xor(vmax, o));
    float ssum = 0.f;
    #pragma unroll
    for (int k = 0; k < 4; ++k) ssum += exp2_hw(vals[k] - vmax);
    #pragma unroll
    for (int o = 32; o; o >>= 1) ssum += __shfl_xor(ssum, o);
    if (lane == 0) {
        const float total2 = vmax + log2_hw(ssum);
        const float loss = -LN2f * total2;
        atomicAdd(out, loss / ((float)tl * (float)Nn));
    }
}

extern "C" void kernel_launch(void* const* d_in, const int* in_sizes, int n_in,
                              void* d_out, int out_size, void* d_ws, size_t ws_size,
                              hipStream_t stream) {
    const float* logits = (const float*)d_in[0];
    const int* targets  = (const int*)d_in[1];
    const int* tlen     = (const int*)d_in[2];
    const int* ilen     = (const int*)d_in[3];
    float* out = (float*)d_out;

    float* wsA = (float*)d_ws;                         // Nn*256
    float* wsB = wsA + Nn * 256;                       // Nn*256
    float* dP  = wsB + Nn * 256;                       // 2 * Nn*Tt (partials / d2)
    float* P1  = dP + (size_t)2 * Nn * Tt;             // tier1 P
    float* P2  = dP + (size_t)Nn * Tt;                 // tier2 P (old layout)

    const size_t base = (size_t)Nn * 512;
    const size_t need1 = (base + (size_t)2 * Nn * Tt + (size_t)Nn * Cc * Tt) * 4;
    const size_t need2 = (base + (size_t)Nn * Tt + (size_t)Nn * Cc * Tt) * 4;

    hipMemsetAsync(d_out, 0, sizeof(float), stream);
    if (ws_size >= need1) {
        ctc_denom_part<<<dim3(4, Nn, 2), 256, 0, stream>>>(logits, dP);
        ctc_prob_sel<true><<<dim3(4, Nn, 8), 256, 0, stream>>>(logits, dP, targets, tlen, P1);
        ctc_fb_kernel<true><<<Nn * 2, 64, 0, stream>>>(P1, targets, tlen, ilen, dP, wsA, wsB);
    } else if (ws_size >= need2) {
        ctc_denom_kernel<<<dim3(4, Nn), 256, 0, stream>>>(logits, dP);
        ctc_prob_sel<false><<<dim3(4, Nn, 8), 256, 0, stream>>>(logits, dP, targets, tlen, P2);
        ctc_fb_kernel<true><<<Nn * 2, 64, 0, stream>>>(P2, targets, tlen, ilen, dP, wsA, wsB);
    } else {
        ctc_denom_part<<<dim3(4, Nn, 2), 256, 0, stream>>>(logits, dP);
        ctc_denom_merge<<<dim3(4, Nn), 256, 0, stream>>>(dP);
        ctc_fb_kernel<false><<<Nn * 2, 64, 0, stream>>>(logits, targets, tlen, ilen, dP, wsA, wsB);
    }
    ctc_combine_kernel<<<Nn, 64, 0, stream>>>(wsA, wsB, targets, tlen, out);
}